// Round 7
// baseline (3956.783 us; speedup 1.0000x reference)
//
#include <hip/hip_runtime.h>
#include <cstdint>
#include <cstddef>

namespace {
constexpr int Dh = 512;   // hidden / emb dim
constexpr int G3 = 1536;  // 3*Dh
constexpr int NB = 256;   // batch
constexpr int SL = 256;   // src len
constexpr int TL = 256;   // trg len
constexpr int NV = 512;   // vocab
}

typedef __attribute__((ext_vector_type(8))) short bf16x8;
typedef __attribute__((ext_vector_type(4))) float f32x4;
typedef unsigned long long u64t;

__device__ __forceinline__ unsigned short f2bf(float f) {
  unsigned int u = __float_as_uint(f);
  u = (u + 0x7FFFu + ((u >> 16) & 1u)) >> 16;  // RNE (finite, small values)
  return (unsigned short)u;
}
__device__ __forceinline__ float bf2f(unsigned short s) {
  return __uint_as_float(((unsigned int)s) << 16);
}

// gi packed layout (consumer-native): [s][b][dt32(16)][l15(16)][8]
// slot n*3+g (n = d16-half within 32-d tile, g = gate), slots 6,7 padding.

// f32 -> bf16 elementwise (optional relu), 4 elems/thread
__global__ __launch_bounds__(256) void cvt_bf16(const float* __restrict__ in,
                                                unsigned short* __restrict__ out,
                                                int n4, int relu) {
  int i = blockIdx.x * 256 + threadIdx.x;
  if (i >= n4) return;
  float4 v = ((const float4*)in)[i];
  if (relu) {
    v.x = fmaxf(v.x, 0.f); v.y = fmaxf(v.y, 0.f);
    v.z = fmaxf(v.z, 0.f); v.w = fmaxf(v.w, 0.f);
  }
  ushort4 o;
  o.x = f2bf(v.x); o.y = f2bf(v.y); o.z = f2bf(v.z); o.w = f2bf(v.w);
  ((ushort4*)out)[i] = o;
}

// Pack Whh (bf16 [1536][512] native) into lane-major fragment order:
// Wpk[dt(16)][slot(6)][kk(16)][lane(64)][8], slot = n*3+g.
// Fragment (dt,slot,kk,lane): W[g*512 + dt*32 + n*16 + (l&15)][kk*32 + (l>>4)*8 .. +8]
__global__ __launch_bounds__(256) void pack_whh(const unsigned short* __restrict__ Wb,
                                                unsigned short* __restrict__ Wpk) {
  const int idx = blockIdx.x * 256 + threadIdx.x;  // 16*6*16*64 = 98304 fragments
  if (idx >= 16 * 6 * 16 * 64) return;
  const int dt = idx / 6144;
  const int rem = idx - dt * 6144;
  const int slot = rem >> 10;
  const int kk = (rem >> 6) & 15;
  const int l = rem & 63;
  const int n = slot / 3, g = slot - n * 3;
  const int row = g * 512 + dt * 32 + n * 16 + (l & 15);
  const int k = kk * 32 + (l >> 4) * 8;
  *(uint4*)(Wpk + (size_t)idx * 8) = *(const uint4*)(Wb + (size_t)row * Dh + k);
}

// C[M,N] = A(bf16) @ W(bf16 [N][K] native rows)^T-as-B + bias, K = 512.
// MFMA 16x16x32. 128x128 tile, BK=64, 4 waves (2x2 x 64x64 quadrants).
// AMODE 0: A row = Abase + idx[row]*K (embedding gather), row m = b*256 + s
// AMODE 1: A row = Abase + ((row&255)*NB + (row>>8))*K (hb_all[t][b], row=b*TL+t)
// OMODE 0: fp32 at row*N+col   OMODE 2: bf16 scattered to packed gi layout
template <int AMODE, int OMODE>
__global__ __launch_bounds__(256) void gemm_bf16(
    const unsigned short* __restrict__ Abase, const int* __restrict__ idx,
    const unsigned short* __restrict__ W, const float* __restrict__ bias,
    void* __restrict__ Cout, int N) {
  __shared__ unsigned short lds_a[8 * 128 * 8];  // 16 KB
  __shared__ unsigned short lds_b[8 * 128 * 8];  // 16 KB
  const int t = threadIdx.x;
  const int n0 = blockIdx.x * 128;
  const int m0 = blockIdx.y * 128;
  const int w = t >> 6, l = t & 63;
  const int mq = (w & 1) * 64, nq = (w >> 1) * 64;
  const int l15 = l & 15, lh = l >> 4;

  const int sm = t & 127;
  const int sk = (t >> 7) * 4;
  const unsigned short* arow;
  if (AMODE == 0) {
    arow = Abase + (size_t)idx[m0 + sm] * Dh;
  } else {
    int row = m0 + sm;
    arow = Abase + ((size_t)(row & 255) * NB + (row >> 8)) * Dh;
  }
  const unsigned short* brow = W + (size_t)(n0 + sm) * Dh;

  f32x4 acc[4][4];
#pragma unroll
  for (int i = 0; i < 4; ++i)
#pragma unroll
    for (int j = 0; j < 4; ++j) acc[i][j] = (f32x4)0.f;

  for (int k0 = 0; k0 < Dh; k0 += 64) {
    __syncthreads();
#pragma unroll
    for (int i = 0; i < 4; ++i) {
      int kc = sk + i;
      *(uint4*)&lds_a[(kc * 128 + sm) * 8] = *(const uint4*)(arow + k0 + kc * 8);
      *(uint4*)&lds_b[(kc * 128 + sm) * 8] = *(const uint4*)(brow + k0 + kc * 8);
    }
    __syncthreads();
#pragma unroll
    for (int q = 0; q < 2; ++q) {
      bf16x8 af[4], bfr[4];
#pragma unroll
      for (int i = 0; i < 4; ++i)
        af[i] = *(const bf16x8*)&lds_a[((q * 4 + lh) * 128 + mq + i * 16 + l15) * 8];
#pragma unroll
      for (int j = 0; j < 4; ++j)
        bfr[j] = *(const bf16x8*)&lds_b[((q * 4 + lh) * 128 + nq + j * 16 + l15) * 8];
#pragma unroll
      for (int i = 0; i < 4; ++i)
#pragma unroll
        for (int j = 0; j < 4; ++j)
          acc[i][j] = __builtin_amdgcn_mfma_f32_16x16x32_bf16(af[i], bfr[j], acc[i][j], 0, 0, 0);
    }
  }

#pragma unroll
  for (int j = 0; j < 4; ++j) {
    const int col = n0 + nq + j * 16 + l15;
    const float bv = bias[col];
#pragma unroll
    for (int i = 0; i < 4; ++i) {
#pragma unroll
      for (int r = 0; r < 4; ++r) {
        const int row = m0 + mq + i * 16 + lh * 4 + r;
        const float v = acc[i][j][r] + bv;
        if (OMODE == 0) {
          ((float*)Cout)[(size_t)row * N + col] = v;
        } else {
          const int b = row >> 8, s = row & 255;      // row = b*256 + s
          const int g = col >> 9, d = col & 511;
          const int dt = d >> 5, nn_ = (d >> 4) & 1, cl = d & 15;
          ((unsigned short*)Cout)[((((size_t)s * NB + b) * 16 + dt) * 16 + cl) * 8 + nn_ * 3 + g] = f2bf(v);
        }
      }
    }
  }
}

// ---- Persistent GRU phase, fence-free system-scope exchange. ----
// 256 WGs x 64 thr (1 wave), 96KB LDS => exactly 1 WG/CU, full residency.
// Wave owns 16 batches x 32 d x 3 gates; W slice in LDS (staged once);
// fp32 h carry in registers; bf16 h exchanged via sc0sc1 (L1/L2-bypass)
// atomics; sync via per-WG flag array polled by the 16-WG batch group.
// Flag certifies the producer's step-s reads AND writes are complete.
__global__ __launch_bounds__(64, 1) void gru_persist2(
    const unsigned short* __restrict__ Wpk,   // [16][6][16][64][8] packed
    const unsigned short* __restrict__ gi,    // packed [s][b][dt][l15][8] (incl. bih)
    const float* __restrict__ bhh,
    const float* __restrict__ h32_init,       // fp32 init (null -> zeros)
    float* __restrict__ h32_final,            // fp32 out (or null)
    unsigned short* __restrict__ hbA,         // enc: ping (pre-zeroed h0); dec: enc-final h
    unsigned short* __restrict__ hbB,         // enc: pong; dec: unused
    unsigned short* __restrict__ hb_all,      // dec: exchange + archive; enc: null
    unsigned int* __restrict__ flags,         // [256] u32, pre-zeroed
    int nsteps) {
  __shared__ unsigned short wl[6 * 16 * 64 * 8];  // 96 KB
  const int wt = blockIdx.x;               // 0..255
  const int b0 = (wt >> 4) * 16;
  const int dt = wt & 15, d0 = dt * 32;
  const int l = threadIdx.x;               // 0..63
  const int l15 = l & 15, lh = l >> 4;

  // ---- stage W slice to LDS once (fragment order matches ds_read pattern) ----
  {
    const uint4* wsrc = (const uint4*)(Wpk + (size_t)dt * 49152);
    uint4* wdst = (uint4*)wl;
#pragma unroll 4
    for (int i = 0; i < 96; ++i) wdst[i * 64 + l] = wsrc[i * 64 + l];
  }
  __syncthreads();

  // biases for this lane's two d-columns
  float br_[2], bz_[2], bn_[2];
#pragma unroll
  for (int n = 0; n < 2; ++n) {
    const int d = d0 + n * 16 + l15;
    br_[n] = bhh[d]; bz_[n] = bhh[512 + d]; bn_[n] = bhh[1024 + d];
  }

  // fp32 h carry
  float hp[2][4];
#pragma unroll
  for (int n = 0; n < 2; ++n)
#pragma unroll
    for (int r = 0; r < 4; ++r)
      hp[n][r] = h32_init ? h32_init[(size_t)(b0 + lh * 4 + r) * Dh + d0 + n * 16 + l15] : 0.f;

  // gi prefetch for step 0
  uint4 gpr[4];
#pragma unroll
  for (int r = 0; r < 4; ++r)
    gpr[r] = *(const uint4*)(gi + ((((size_t)0 * NB + b0 + lh * 4 + r) * 16 + dt) * 16 + l15) * 8);

  const unsigned int* fgrp = flags + (wt & ~15);

  for (int s = 0; s < nsteps; ++s) {
    const unsigned short* rdbuf;
    unsigned short* wrbuf;
    if (hb_all) {
      rdbuf = (s == 0) ? hbA : hb_all + (size_t)(s - 1) * NB * Dh;
      wrbuf = hb_all + (size_t)s * NB * Dh;
    } else {
      rdbuf = (s & 1) ? hbB : hbA;
      wrbuf = (s & 1) ? hbA : hbB;
    }

    // ---- wait for batch-group's step-(s) inputs (producers' flag = s) ----
    if (s > 0) {
      const unsigned int tgt = (unsigned)s;
      unsigned int f;
      do {
        f = __hip_atomic_load(fgrp + l15, __ATOMIC_RELAXED, __HIP_MEMORY_SCOPE_SYSTEM);
        if (__all((int)(f >= tgt))) break;
        __builtin_amdgcn_s_sleep(1);
      } while (true);
      asm volatile("" ::: "memory");  // no hoisting of data loads above poll
    }

    // ---- A-fragments: system-scope u64 loads (bypass stale L1/L2) ----
    const u64t* ap = (const u64t*)(rdbuf + (size_t)(b0 + l15) * Dh + lh * 8);
    bf16x8 af[16];
#pragma unroll
    for (int kk = 0; kk < 16; ++kk) {
      union { u64t q[2]; bf16x8 v; } u;
      u.q[0] = __hip_atomic_load(ap + kk * 8, __ATOMIC_RELAXED, __HIP_MEMORY_SCOPE_SYSTEM);
      u.q[1] = __hip_atomic_load(ap + kk * 8 + 1, __ATOMIC_RELAXED, __HIP_MEMORY_SCOPE_SYSTEM);
      af[kk] = u.v;
    }

    // ---- 96 MFMA from LDS-resident W ----
    f32x4 acc[6];
#pragma unroll
    for (int sl_ = 0; sl_ < 6; ++sl_) acc[sl_] = (f32x4)0.f;
#pragma unroll
    for (int sl_ = 0; sl_ < 6; ++sl_)
#pragma unroll
      for (int kk = 0; kk < 16; ++kk) {
        bf16x8 bv = *(const bf16x8*)&wl[((sl_ * 16 + kk) * 64 + l) * 8];
        acc[sl_] = __builtin_amdgcn_mfma_f32_16x16x32_bf16(af[kk], bv, acc[sl_], 0, 0, 0);
      }

    // ---- gates (lane-local) ----
#pragma unroll
    for (int n = 0; n < 2; ++n)
#pragma unroll
      for (int r = 0; r < 4; ++r) {
        const unsigned short* gp = (const unsigned short*)&gpr[r];
        const float gir = bf2f(gp[n * 3 + 0]);
        const float giz = bf2f(gp[n * 3 + 1]);
        const float gin = bf2f(gp[n * 3 + 2]);
        const float rr = 1.f / (1.f + __expf(-(gir + acc[n * 3 + 0][r] + br_[n])));
        const float zz = 1.f / (1.f + __expf(-(giz + acc[n * 3 + 1][r] + bz_[n])));
        const float x2 = gin + rr * (acc[n * 3 + 2][r] + bn_[n]);
        const float nn = 1.f - 2.f / (__expf(2.f * x2) + 1.f);  // tanh
        hp[n][r] = (1.f - zz) * nn + zz * hp[n][r];
      }

    // ---- publish bf16 h: pack d-adjacent pairs, system-scope u32 stores ----
#pragma unroll
    for (int n = 0; n < 2; ++n)
#pragma unroll
      for (int r = 0; r < 4; ++r) {
        const float po = __shfl_xor(hp[n][r], 1, 64);
        if ((l15 & 1) == 0) {
          const unsigned int pk = (unsigned)f2bf(hp[n][r]) | ((unsigned)f2bf(po) << 16);
          const int b = b0 + lh * 4 + r, d = d0 + n * 16 + l15;
          __hip_atomic_store((unsigned int*)(wrbuf + (size_t)b * Dh + d), pk,
                             __ATOMIC_RELAXED, __HIP_MEMORY_SCOPE_SYSTEM);
        }
      }

    if (s + 1 < nsteps) {
      // drain data stores, then raise flag (relaxed system store; no fences)
      asm volatile("s_waitcnt vmcnt(0)" ::: "memory");
      if (l == 0)
        __hip_atomic_store(flags + wt, (unsigned)(s + 1), __ATOMIC_RELAXED,
                           __HIP_MEMORY_SCOPE_SYSTEM);
      // prefetch next step's gi under the upcoming poll
#pragma unroll
      for (int r = 0; r < 4; ++r)
        gpr[r] = *(const uint4*)(gi + ((((size_t)(s + 1) * NB + b0 + lh * 4 + r) * 16 + dt) * 16 + l15) * 8);
    }
  }

  if (h32_final) {
#pragma unroll
    for (int n = 0; n < 2; ++n)
#pragma unroll
      for (int r = 0; r < 4; ++r)
        h32_final[(size_t)(b0 + lh * 4 + r) * Dh + d0 + n * 16 + l15] = hp[n][r];
  }
}

// in-place log_softmax over last dim (512); one wave per row
__global__ __launch_bounds__(256) void logsoftmax512(float* __restrict__ x) {
  const int row = blockIdx.x * 4 + (threadIdx.x >> 6);
  const int lane = threadIdx.x & 63;
  float* p = x + (size_t)row * NV + lane * 8;
  float4 v0 = *(const float4*)p;
  float4 v1 = *(const float4*)(p + 4);
  float m = fmaxf(fmaxf(fmaxf(v0.x, v0.y), fmaxf(v0.z, v0.w)),
                  fmaxf(fmaxf(v1.x, v1.y), fmaxf(v1.z, v1.w)));
#pragma unroll
  for (int o = 1; o < 64; o <<= 1) m = fmaxf(m, __shfl_xor(m, o, 64));
  float s = expf(v0.x - m) + expf(v0.y - m) + expf(v0.z - m) + expf(v0.w - m) +
            expf(v1.x - m) + expf(v1.y - m) + expf(v1.z - m) + expf(v1.w - m);
#pragma unroll
  for (int o = 1; o < 64; o <<= 1) s += __shfl_xor(s, o, 64);
  const float ls = m + logf(s);
  v0.x -= ls; v0.y -= ls; v0.z -= ls; v0.w -= ls;
  v1.x -= ls; v1.y -= ls; v1.z -= ls; v1.w -= ls;
  *(float4*)p = v0;
  *(float4*)(p + 4) = v1;
}

extern "C" void kernel_launch(void* const* d_in, const int* in_sizes, int n_in,
                              void* d_out, int out_size, void* d_ws, size_t ws_size,
                              hipStream_t stream) {
  (void)in_sizes; (void)n_in; (void)out_size; (void)ws_size;
  const int* src = (const int*)d_in[0];
  const int* trg = (const int*)d_in[1];
  const float* enc_emb = (const float*)d_in[4];
  const float* enc_Wih = (const float*)d_in[5];
  const float* enc_Whh = (const float*)d_in[6];
  const float* enc_bih = (const float*)d_in[7];
  const float* enc_bhh = (const float*)d_in[8];
  const float* dec_emb = (const float*)d_in[9];
  const float* dec_Wih = (const float*)d_in[10];
  const float* dec_Whh = (const float*)d_in[11];
  const float* dec_bih = (const float*)d_in[12];
  const float* dec_bhh = (const float*)d_in[13];
  const float* out_W = (const float*)d_in[14];
  const float* out_b = (const float*)d_in[15];

  char* ws = (char*)d_ws;
  size_t off = 0;
  auto alloc = [&](size_t bytes) -> char* {
    char* p = ws + off;
    off += (bytes + 255) & ~(size_t)255;
    return p;
  };
  typedef unsigned short u16;
  u16* gi = (u16*)alloc((size_t)NB * SL * 16 * 16 * 8 * 2);  // 268 MB packed
  u16* hb_all = (u16*)alloc((size_t)TL * NB * Dh * 2);       // 67 MB (dec exchange+archive)
  float* h_enc = (float*)alloc((size_t)NB * Dh * 4);
  u16* hbA = (u16*)alloc((size_t)NB * Dh * 2);
  u16* hbB = (u16*)alloc((size_t)NB * Dh * 2);
  u16* embB_e = (u16*)alloc((size_t)NV * Dh * 2);
  u16* embB_d = (u16*)alloc((size_t)NV * Dh * 2);            // relu pre-applied
  u16* WihB_e = (u16*)alloc((size_t)G3 * Dh * 2);
  u16* WhhB_e = (u16*)alloc((size_t)G3 * Dh * 2);
  u16* WihB_d = (u16*)alloc((size_t)G3 * Dh * 2);
  u16* WhhB_d = (u16*)alloc((size_t)G3 * Dh * 2);
  u16* outWB = (u16*)alloc((size_t)NV * Dh * 2);
  u16* Wpk_e = (u16*)alloc((size_t)16 * 6 * 16 * 64 * 8 * 2);  // 1.57 MB
  u16* Wpk_d = (u16*)alloc((size_t)16 * 6 * 16 * 64 * 8 * 2);
  unsigned int* flags = (unsigned int*)alloc(2 * 256 * 4);     // [enc 256][dec 256]

  cvt_bf16<<<(NV * Dh / 4 + 255) / 256, 256, 0, stream>>>(enc_emb, embB_e, NV * Dh / 4, 0);
  cvt_bf16<<<(NV * Dh / 4 + 255) / 256, 256, 0, stream>>>(dec_emb, embB_d, NV * Dh / 4, 1);
  cvt_bf16<<<(G3 * Dh / 4 + 255) / 256, 256, 0, stream>>>(enc_Wih, WihB_e, G3 * Dh / 4, 0);
  cvt_bf16<<<(G3 * Dh / 4 + 255) / 256, 256, 0, stream>>>(enc_Whh, WhhB_e, G3 * Dh / 4, 0);
  cvt_bf16<<<(G3 * Dh / 4 + 255) / 256, 256, 0, stream>>>(dec_Wih, WihB_d, G3 * Dh / 4, 0);
  cvt_bf16<<<(G3 * Dh / 4 + 255) / 256, 256, 0, stream>>>(dec_Whh, WhhB_d, G3 * Dh / 4, 0);
  cvt_bf16<<<(NV * Dh / 4 + 255) / 256, 256, 0, stream>>>(out_W, outWB, NV * Dh / 4, 0);
  pack_whh<<<384, 256, 0, stream>>>(WhhB_e, Wpk_e);
  pack_whh<<<384, 256, 0, stream>>>(WhhB_d, Wpk_d);
  hipMemsetAsync(hbA, 0, (size_t)NB * Dh * 2, stream);   // bf16 h0 = 0
  hipMemsetAsync(flags, 0, 2 * 256 * 4, stream);         // reset all flags (per replay)

  // encoder gi (packed layout)
  dim3 ggi(G3 / 128, NB * SL / 128);
  gemm_bf16<0, 2><<<ggi, 256, 0, stream>>>(embB_e, src, WihB_e, enc_bih, gi, G3);

  // ---- encoder recurrence: one persistent kernel, fence-free sync ----
  gru_persist2<<<dim3(256), 64, 0, stream>>>(Wpk_e, gi, enc_bhh, nullptr, h_enc,
                                             hbA, hbB, nullptr, flags, SL);
  // SL=256 even -> final bf16 h in hbA; fp32 in h_enc

  // decoder gi (packed layout; stream-ordered after encoder reads done)
  gemm_bf16<0, 2><<<ggi, 256, 0, stream>>>(embB_d, trg, WihB_d, dec_bih, gi, G3);

  // ---- decoder recurrence: persistent; hb_all is both exchange and archive ----
  gru_persist2<<<dim3(256), 64, 0, stream>>>(Wpk_d, gi, dec_bhh, h_enc, nullptr,
                                             hbA, hbB, hb_all, flags + 256, TL);

  // logits = hb_all @ out_W^T + out_b -> d_out (fp32), then log_softmax
  dim3 glg(NV / 128, NB * TL / 128);
  gemm_bf16<1, 0><<<glg, 256, 0, stream>>>(hb_all, nullptr, outWB, out_b, d_out, NV);
  logsoftmax512<<<NB * TL / 4, 256, 0, stream>>>((float*)d_out);
}